// Round 19
// baseline (131.692 us; speedup 1.0000x reference)
//
#include <hip/hip_runtime.h>
#include <stdint.h>

typedef unsigned short u16;
typedef unsigned int u32;
typedef __attribute__((ext_vector_type(8))) short short8;
typedef __attribute__((ext_vector_type(4))) float f32x4;

#define EMBED 1024
#define HEADS 16
#define HDIM 64
#define NBATCH 2
#define SLEN 64
#define RLEN 2048
#define TOTKV (SLEN + RLEN)   // 2112

struct WSrc { const float* p[10]; };

// ---------- small helpers ----------
__device__ __forceinline__ float bf2f(u16 u) {
  union { u32 i; float f; } v; v.i = ((u32)u) << 16; return v.f;
}
__device__ __forceinline__ u16 f2bf(float f) {
  union { float f; u32 i; } v; v.f = f;
  return (u16)((v.i + 0x7fffu + ((v.i >> 16) & 1u)) >> 16);  // RNE
}
__device__ __forceinline__ void up2(u32 u, float& a, float& b) {
  union { u32 i; float f; } x, y;
  x.i = u << 16; y.i = u & 0xffff0000u;
  a = x.f; b = y.f;
}
__device__ __forceinline__ void gload16(const void* g, void* l) {
  __builtin_amdgcn_global_load_lds((const __attribute__((address_space(1))) u32*)g,
                                   (__attribute__((address_space(3))) u32*)l, 16, 0, 0);
}

// ---------- fused pre-pass (r11/r14/r17/r18 proven) ----------
__global__ __launch_bounds__(256)
void prepass_k(WSrc wsrc, u16* __restrict__ Wt,
               const float* __restrict__ sum_x, u16* __restrict__ sxb,
               const float* __restrict__ reg_x, u16* __restrict__ rxb,
               float* __restrict__ cosT, float* __restrict__ sinT)
{
  __shared__ float tile[64][65];
  int b = blockIdx.x, t = threadIdx.x;
  if (b < 2560) {
    int z = b >> 8, rem = b & 255;
    int n0 = (rem & 15) * 64, k0 = (rem >> 4) * 64;
    const float* src = wsrc.p[z];
    u16* out = Wt + (size_t)z * (EMBED * (size_t)EMBED);
    int r0 = t >> 4, c0 = (t & 15) * 4;
#pragma unroll
    for (int i = 0; i < 4; ++i) {
      int r = i * 16 + r0;
      float4 v = *(const float4*)(src + (size_t)(k0 + r) * EMBED + n0 + c0);
      tile[r][c0] = v.x; tile[r][c0 + 1] = v.y; tile[r][c0 + 2] = v.z; tile[r][c0 + 3] = v.w;
    }
    __syncthreads();
#pragma unroll
    for (int i = 0; i < 4; ++i) {
      int n = i * 16 + r0;
      uint2 o;
      o.x = (u32)f2bf(tile[c0][n]) | ((u32)f2bf(tile[c0 + 1][n]) << 16);
      o.y = (u32)f2bf(tile[c0 + 2][n]) | ((u32)f2bf(tile[c0 + 3][n]) << 16);
      *(uint2*)(out + (size_t)(n0 + n) * EMBED + k0 + c0) = o;
    }
  } else if (b < 6656) {
    int i = ((b - 2560) * 256 + t) * 4;
    if (i < (int)((size_t)NBATCH * RLEN * EMBED)) {
      float4 v = *(const float4*)(reg_x + i);
      uint2 o;
      o.x = (u32)f2bf(v.x) | ((u32)f2bf(v.y) << 16);
      o.y = (u32)f2bf(v.z) | ((u32)f2bf(v.w) << 16);
      *(uint2*)(rxb + i) = o;
    }
  } else if (b < 6784) {
    int i = ((b - 6656) * 256 + t) * 4;
    if (i < (int)((size_t)NBATCH * SLEN * EMBED)) {
      float4 v = *(const float4*)(sum_x + i);
      uint2 o;
      o.x = (u32)f2bf(v.x) | ((u32)f2bf(v.y) << 16);
      o.y = (u32)f2bf(v.z) | ((u32)f2bf(v.w) << 16);
      *(uint2*)(sxb + i) = o;
    }
  } else {
    int idx = (b - 6784) * 256 + t;
    if (idx < TOTKV * 32) {
      int pos = idx >> 5, i = idx & 31;
      float inv = powf(10000.0f, -(float)i / 32.0f);
      float a = (float)pos * inv;
      float s, c;
      sincosf(a, &s, &c);
      cosT[idx] = c; sinT[idx] = s;
    }
  }
}

// ---------- BK=32 core with K range (r17/r18 proven) ----------
__device__ __forceinline__ void gemm_core32r(const u16* __restrict__ A, const u16* __restrict__ Wt,
                                             int rowBase, int colBase, int lane, int w,
                                             u16* As, u16* Bs, f32x4 (&acc)[4][4],
                                             int kBeg, int kEnd) {
  int wr = w >> 1, wc = w & 1;
  int lr = lane >> 2, l4 = lane & 3;
  const u16* srcA0 = A + (size_t)(rowBase + w * 16 + lr) * EMBED + l4 * 8;
  const u16* srcA1 = srcA0 + 64 * EMBED;
  const u16* srcB0 = Wt + (size_t)(colBase + w * 16 + lr) * EMBED + l4 * 8;
  const u16* srcB1 = srcB0 + 64 * EMBED;
  u16* dstA = As + w * 512;
  u16* dstB = Bs + w * 512;
  int aoff = (lane & 15) * 32 + (lane >> 4) * 8;
  const u16* fA = As + wr * 2048 + aoff;
  const u16* fB = Bs + wc * 2048 + aoff;

  for (int k0 = kBeg; k0 < kEnd; k0 += 32) {
    gload16(srcA0 + k0, dstA);
    gload16(srcA1 + k0, dstA + 2048);
    gload16(srcB0 + k0, dstB);
    gload16(srcB1 + k0, dstB + 2048);
    __syncthreads();
    short8 af[4], bfv[4];
#pragma unroll
    for (int mi = 0; mi < 4; ++mi) af[mi] = *(const short8*)(fA + mi * 512);
#pragma unroll
    for (int ni = 0; ni < 4; ++ni) bfv[ni] = *(const short8*)(fB + ni * 512);
#pragma unroll
    for (int mi = 0; mi < 4; ++mi)
#pragma unroll
      for (int ni = 0; ni < 4; ++ni)
        acc[mi][ni] = __builtin_amdgcn_mfma_f32_16x16x32_bf16(af[mi], bfv[ni], acc[mi][ni], 0, 0, 0);
    __syncthreads();
  }
}

// mode 0: bf16 headsplit + rope; mode 1: bf16 headsplit; mode 2: f32 row-major
__device__ __forceinline__ void gemm_epilogue(f32x4 (&acc)[4][4], int mode, void* outp,
                                              const float* bias, int rowBase, int colBase,
                                              int L, int posoff, int lane, int w,
                                              const float* cosT, const float* sinT) {
  int wr = w >> 1, wc = w & 1;
  int c15 = lane & 15, rgrp = (lane >> 4) * 4;
  if (mode == 2) {
    float* out = (float*)outp;
#pragma unroll
    for (int mi = 0; mi < 4; ++mi)
#pragma unroll
      for (int r = 0; r < 4; ++r) {
        int m = rowBase + wr * 64 + mi * 16 + rgrp + r;
#pragma unroll
        for (int ni = 0; ni < 4; ++ni) {
          int n = colBase + wc * 64 + ni * 16 + c15;
          out[(size_t)m * EMBED + n] = acc[mi][ni][r] + bias[n];
        }
      }
  } else {
    u16* out = (u16*)outp;
    int h = (colBase >> 6) + wc;
    bool dorope = (mode == 0);
#pragma unroll
    for (int mi = 0; mi < 4; ++mi)
#pragma unroll
      for (int r = 0; r < 4; ++r) {
        int m = rowBase + wr * 64 + mi * 16 + rgrp + r;
        int bidx = (m >= L) ? 1 : 0;
        int l = m - bidx * L;
        size_t obase = ((size_t)(bidx * HEADS + h) * L + l) * HDIM;
        if (dorope) {
          int pos = posoff + l;
#pragma unroll
          for (int ni = 0; ni < 2; ++ni) {
            int d = ni * 16 + c15;
            float c = cosT[pos * 32 + d], s = sinT[pos * 32 + d];
            float x0 = acc[mi][ni][r] + bias[h * 64 + d];
            float x2 = acc[mi][ni + 2][r] + bias[h * 64 + d + 32];
            out[obase + d]      = f2bf(x0 * c - x2 * s);
            out[obase + d + 32] = f2bf(x2 * c + x0 * s);
          }
        } else {
#pragma unroll
          for (int ni = 0; ni < 4; ++ni) {
            int d = ni * 16 + c15;
            out[obase + d] = f2bf(acc[mi][ni][r] + bias[h * 64 + d]);
          }
        }
      }
  }
}

// ---------- fused QKV: grid (8, 36, 3). by<4 -> LIGHT sum split-K partial (dispatched
// first, drains ahead of heavies); by>=4 -> heavy reg tile (row by-4), BK=32 core. ----------
__global__ __launch_bounds__(256)
void qkvf_k(const u16* __restrict__ rxb, const u16* __restrict__ sxb,
            const u16* __restrict__ Wt_all,
            const float* b4, const float* b5, const float* b6,
            u16* Qr, u16* Kr, u16* Vr, float* __restrict__ part,
            const float* __restrict__ cosT, const float* __restrict__ sinT)
{
  __shared__ __align__(16) u16 As[4096];
  __shared__ __align__(16) u16 Bs[4096];
  int bx = blockIdx.x, by = blockIdx.y, bz = blockIdx.z;
  int lane = threadIdx.x & 63, w = threadIdx.x >> 6;
  int colBase = bx * 128;

  if (by < 4) {
    // light: sum QKV split-K partial, K quarter by
    const u16* Wt = Wt_all + (size_t)bz * EMBED * EMBED;
    f32x4 acc[4][4] = {};
    gemm_core32r(sxb, Wt, 0, colBase, lane, w, As, Bs, acc, by * 256, by * 256 + 256);
    float* outp = part + ((size_t)(bz * 4 + by)) * (128 * EMBED);
    int wr = w >> 1, wc = w & 1, c15 = lane & 15, rgrp = (lane >> 4) * 4;
#pragma unroll
    for (int mi = 0; mi < 4; ++mi)
#pragma unroll
      for (int r = 0; r < 4; ++r) {
        int m = wr * 64 + mi * 16 + rgrp + r;
#pragma unroll
        for (int ni = 0; ni < 4; ++ni) {
          int n = colBase + wc * 64 + ni * 16 + c15;
          outp[(size_t)m * EMBED + n] = acc[mi][ni][r];
        }
      }
  } else {
    // heavy: reg QKV tile
    const u16* Wt = Wt_all + (size_t)(4 + bz) * EMBED * EMBED;
    const float* bias = (bz == 0) ? b4 : ((bz == 1) ? b5 : b6);
    u16* out = (bz == 0) ? Qr : (bz == 1 ? Kr : Vr);
    int mode = (bz < 2) ? 0 : 1;
    f32x4 acc[4][4] = {};
    gemm_core32r(rxb, Wt, (by - 4) * 128, colBase, lane, w, As, Bs, acc, 0, EMBED);
    gemm_epilogue(acc, mode, out, bias, (by - 4) * 128, colBase, RLEN, SLEN, lane, w, cosT, sinT);
  }
}

// ---------- generic split-K partial: grid (8, 4, 3) (r18 proven; used for sattn) ----------
__global__ __launch_bounds__(256)
void splitk_k(const u16* __restrict__ A, const u16* __restrict__ Wt_all,
              int wi0, int wi1, int wi2, float* __restrict__ part)
{
  __shared__ __align__(16) u16 As[4096];
  __shared__ __align__(16) u16 Bs[4096];
  int bx = blockIdx.x, ks = blockIdx.y, bz = blockIdx.z;
  int lane = threadIdx.x & 63, w = threadIdx.x >> 6;
  int widx = (bz == 0) ? wi0 : ((bz == 1) ? wi1 : wi2);
  const u16* Wt = Wt_all + (size_t)widx * EMBED * EMBED;
  int colBase = bx * 128;

  f32x4 acc[4][4] = {};
  gemm_core32r(A, Wt, 0, colBase, lane, w, As, Bs, acc, ks * 256, ks * 256 + 256);

  float* outp = part + ((size_t)(bz * 4 + ks)) * (128 * EMBED);
  int wr = w >> 1, wc = w & 1, c15 = lane & 15, rgrp = (lane >> 4) * 4;
#pragma unroll
  for (int mi = 0; mi < 4; ++mi)
#pragma unroll
    for (int r = 0; r < 4; ++r) {
      int m = wr * 64 + mi * 16 + rgrp + r;
#pragma unroll
      for (int ni = 0; ni < 4; ++ni) {
        int n = colBase + wc * 64 + ni * 16 + c15;
        outp[(size_t)m * EMBED + n] = acc[mi][ni][r];
      }
    }
}

// ---------- sum QKV reduce: grid (256, 3); rope on z<2 (r17/r18 proven) ----------
__global__ __launch_bounds__(256)
void sumqkv_reduce_k(const float* __restrict__ part,
                     const float* b0, const float* b1, const float* b2,
                     u16* Qs, u16* Ks, u16* Vs,
                     const float* __restrict__ cosT, const float* __restrict__ sinT)
{
  int z = blockIdx.y;
  int idx = blockIdx.x * 256 + threadIdx.x;
  int m = idx >> 9, rest = idx & 511;
  int h = rest >> 5, d = rest & 31;
  const float* p = part + (size_t)z * 4 * (128 * EMBED);
  const float* bias = (z == 0) ? b0 : ((z == 1) ? b1 : b2);
  u16* out = (z == 0) ? Qs : ((z == 1) ? Ks : Vs);
  int n0 = h * 64 + d, n1 = n0 + 32;
  float a0 = 0.f, a1 = 0.f;
#pragma unroll
  for (int ks = 0; ks < 4; ++ks) {
    a0 += p[(size_t)ks * (128 * EMBED) + (size_t)m * EMBED + n0];
    a1 += p[(size_t)ks * (128 * EMBED) + (size_t)m * EMBED + n1];
  }
  a0 += bias[n0];
  a1 += bias[n1];
  int b = m >> 6, l = m & 63;
  size_t obase = ((size_t)(b * HEADS + h) * SLEN + l) * HDIM;
  if (z < 2) {
    float c = cosT[l * 32 + d], s = sinT[l * 32 + d];
    out[obase + d]      = f2bf(a0 * c - a1 * s);
    out[obase + d + 32] = f2bf(a1 * c + a0 * s);
  } else {
    out[obase + d]      = f2bf(a0);
    out[obase + d + 32] = f2bf(a1);
  }
}

// ---------- sattn reduce: grid (256, 3) (r18 proven) ----------
__global__ __launch_bounds__(256)
void sat_reduce_k(const float* __restrict__ part,
                  const float* b0, const float* b1, const float* b2,
                  u16* Ks2, u16* Vs2, float* __restrict__ outS)
{
  int z = blockIdx.y;
  int idx = blockIdx.x * 256 + threadIdx.x;
  int m = idx >> 9, rest = idx & 511;
  int h = rest >> 5, d = rest & 31;
  const float* p = part + (size_t)z * 4 * (128 * EMBED);
  const float* bias = (z == 0) ? b0 : ((z == 1) ? b1 : b2);
  int n0 = h * 64 + d, n1 = n0 + 32;
  float a0 = 0.f, a1 = 0.f;
#pragma unroll
  for (int ks = 0; ks < 4; ++ks) {
    a0 += p[(size_t)ks * (128 * EMBED) + (size_t)m * EMBED + n0];
    a1 += p[(size_t)ks * (128 * EMBED) + (size_t)m * EMBED + n1];
  }
  a0 += bias[n0];
  a1 += bias[n1];
  if (z < 2) {
    u16* out = (z == 0) ? Ks2 : Vs2;
    int b = m >> 6, l = m & 63;
    size_t obase = ((size_t)(b * HEADS + h) * SLEN + l) * HDIM;
    out[obase + d]      = f2bf(a0);
    out[obase + d + 32] = f2bf(a1);
  } else {
    outS[(size_t)m * EMBED + n0] = a0;
    outS[(size_t)m * EMBED + n1] = a1;
  }
}

// ---------- 128x64-tile GEMM, BK=64 (r13/r14/r17/r18 green): reg out-projection ----------
__global__ __launch_bounds__(256)
void gemm64_k(const u16* __restrict__ A, const u16* __restrict__ Wt,
              const float* __restrict__ bias, float* __restrict__ out)
{
  __shared__ __align__(128) u16 As[8192];   // 128 x 64
  __shared__ __align__(128) u16 Bs[4096];   // 64 x 64
  int rowBase = blockIdx.y * 128, colBase = blockIdx.x * 64;
  int lane = threadIdx.x & 63, w = threadIdx.x >> 6;
  int lrow = lane >> 3, lcol = ((lane & 7) ^ lrow) * 8;

  const u16* srcA = A + (size_t)(rowBase + w * 16 + lrow) * EMBED + lcol;
  const u16* srcB = Wt + (size_t)(colBase + w * 16 + lrow) * EMBED + lcol;
  u16* dA = As + w * 1024;
  u16* dB = Bs + w * 1024;
  int l15 = lane & 15, lg = lane >> 4;
  int aoff = l15 * 64 + ((lg ^ (l15 & 7)) * 8);
  const u16* fA = As + w * 2048 + aoff;
  const u16* fB = Bs + aoff;

  f32x4 acc[2][4] = {};
  for (int k0 = 0; k0 < EMBED; k0 += 64) {
    gload16(srcA + k0, dA);
    gload16(srcA + 8 * EMBED + k0, dA + 512);
    gload16(srcA + 64 * EMBED + k0, dA + 4096);
    gload16(srcA + 72 * EMBED + k0, dA + 4608);
    gload16(srcB + k0, dB);
    gload16(srcB + 8 * EMBED + k0, dB + 512);
    __syncthreads();
#pragma unroll
    for (int ks = 0; ks < 2; ++ks) {
      const u16* fAk = (const u16*)((uintptr_t)fA ^ (unsigned)(ks << 6));
      const u16* fBk = (const u16*)((uintptr_t)fB ^ (unsigned)(ks << 6));
      short8 af[2], bfv[4];
#pragma unroll
      for (int mi = 0; mi < 2; ++mi) af[mi] = *(const short8*)(fAk + mi * 1024);
#pragma unroll
      for (int ni = 0; ni < 4; ++ni) bfv[ni] = *(const short8*)(fBk + ni * 1024);
#pragma unroll
      for (int mi = 0; mi < 2; ++mi)
#pragma unroll
        for (int ni = 0; ni < 4; ++ni)
          acc[mi][ni] = __builtin_amdgcn_mfma_f32_16x16x32_bf16(af[mi], bfv[ni], acc[mi][ni], 0, 0, 0);
    }
    __syncthreads();
  }

  int c15 = lane & 15, rgrp = (lane >> 4) * 4;
#pragma unroll
  for (int mi = 0; mi < 2; ++mi)
#pragma unroll
    for (int r = 0; r < 4; ++r) {
      int m = rowBase + w * 32 + mi * 16 + rgrp + r;
#pragma unroll
      for (int ni = 0; ni < 4; ++ni) {
        int n = colBase + ni * 16 + c15;
        out[(size_t)m * EMBED + n] = acc[mi][ni][r] + bias[n];
      }
    }
}

// ---------- attention helpers ----------
__device__ __forceinline__ void loadq(const u16* qrow, float* qf) {
  const uint4* qp = (const uint4*)qrow;
#pragma unroll
  for (int c = 0; c < 8; ++c) {
    uint4 u = qp[c];
    up2(u.x, qf[c * 8 + 0], qf[c * 8 + 1]);
    up2(u.y, qf[c * 8 + 2], qf[c * 8 + 3]);
    up2(u.z, qf[c * 8 + 4], qf[c * 8 + 5]);
    up2(u.w, qf[c * 8 + 6], qf[c * 8 + 7]);
  }
}
__device__ __forceinline__ float dot64(const float* qf, const u16* krow) {
  const uint4* kp = (const uint4*)krow;
  float s = 0.f;
#pragma unroll
  for (int c = 0; c < 8; ++c) {
    uint4 u = kp[c];
    float a0, a1, a2, a3, a4, a5, a6, a7;
    up2(u.x, a0, a1); up2(u.y, a2, a3); up2(u.z, a4, a5); up2(u.w, a6, a7);
    s += qf[c * 8 + 0] * a0 + qf[c * 8 + 1] * a1 + qf[c * 8 + 2] * a2 + qf[c * 8 + 3] * a3
       + qf[c * 8 + 4] * a4 + qf[c * 8 + 5] * a5 + qf[c * 8 + 6] * a6 + qf[c * 8 + 7] * a7;
  }
  return s;
}

// ---------- stage-1 attention: one query per wave ----------
__global__ __launch_bounds__(256)
void attn1_k(const u16* __restrict__ Qs, const u16* __restrict__ Ks,
             const u16* __restrict__ Vs, const u16* __restrict__ Kr,
             const u16* __restrict__ Vr, u16* __restrict__ outA)
{
  int gw = blockIdx.x * 4 + (threadIdx.x >> 6);
  int bh = gw >> 6, qi = gw & 63;
  int b = bh >> 4, h = bh & 15;
  int lane = threadIdx.x & 63;
  const u16* qB = Qs + (size_t)bh * SLEN * HDIM;
  const u16* kS = Ks + (size_t)bh * SLEN * HDIM;
  const u16* vS = Vs + (size_t)bh * SLEN * HDIM;
  const u16* kR = Kr + (size_t)bh * RLEN * HDIM;
  const u16* vR = Vr + (size_t)bh * RLEN * HDIM;

  float qf[64];
  loadq(qB + qi * HDIM, qf);
  bool v1 = (lane <= qi);
  bool v2 = (lane < 32);
  float s1 = v1 ? dot64(qf, kS + lane * HDIM) : 0.f;
  float s2 = v2 ? dot64(qf, kR + (qi * 32 + lane) * HDIM) : 0.f;
  float sc1 = v1 ? s1 * 0.125f : -1e30f;
  float sc2 = v2 ? s2 * 0.125f : -1e30f;
  float mx = fmaxf(sc1, sc2);
#pragma unroll
  for (int off = 32; off; off >>= 1) mx = fmaxf(mx, __shfl_xor(mx, off));
  float e1 = v1 ? __expf(sc1 - mx) : 0.f;
  float e2 = v2 ? __expf(sc2 - mx) : 0.f;
  float sm = e1 + e2;
#pragma unroll
  for (int off = 32; off; off >>= 1) sm += __shfl_xor(sm, off);
  float inv = 1.f / sm;

  float a0 = 0.f, a1 = 0.f, a2 = 0.f, a3 = 0.f;
  const u16* vrow = vR + (size_t)qi * 32 * HDIM + lane;
#pragma unroll
  for (int j = 0; j < 64; j += 4) {
    a0 += __shfl(e1, j + 0) * bf2f(vS[(j + 0) * HDIM + lane]);
    a1 += __shfl(e1, j + 1) * bf2f(vS[(j + 1) * HDIM + lane]);
    a2 += __shfl(e1, j + 2) * bf2f(vS[(j + 2) * HDIM + lane]);
    a3 += __shfl(e1, j + 3) * bf2f(vS[(j + 3) * HDIM + lane]);
  }
#pragma unroll
  for (int j = 0; j < 32; j += 4) {
    a0 += __shfl(e2, j + 0) * bf2f(vrow[(j + 0) * HDIM]);
    a1 += __shfl(e2, j + 1) * bf2f(vrow[(j + 1) * HDIM]);
    a2 += __shfl(e2, j + 2) * bf2f(vrow[(j + 2) * HDIM]);
    a3 += __shfl(e2, j + 3) * bf2f(vrow[(j + 3) * HDIM]);
  }
  float accv = (a0 + a1) + (a2 + a3);
  outA[((size_t)(b * SLEN + qi)) * EMBED + h * HDIM + lane] = f2bf(accv * inv);
}

// ---------- stage-2 attention: MFMA per (b,h,bar) block (r14/r17/r18 green) ----------
__global__ __launch_bounds__(256)
void attn2_k(const u16* __restrict__ Qr, const u16* __restrict__ Kr,
             const u16* __restrict__ Vr, const u16* __restrict__ Ks2,
             const u16* __restrict__ Vs2, u16* __restrict__ outA)
{
  __shared__ __align__(16) float Sf[32][104];
  __shared__ __align__(16) u16 Pb[32][104];
  __shared__ __align__(16) u16 Vt[64][104];

  int bar = blockIdx.x, bh = blockIdx.y;
  int b = bh >> 4, h = bh & 15;
  int nS = bar + 1;
  int tid = threadIdx.x, lane = tid & 63, w = tid >> 6;
  int l15 = lane & 15, lg = lane >> 4;

  const u16* qB = Qr + ((size_t)bh * RLEN + bar * 32) * HDIM;
  const u16* kS = Ks2 + (size_t)bh * SLEN * HDIM;
  const u16* kR = Kr + ((size_t)bh * RLEN + bar * 32) * HDIM;
  const u16* vS = Vs2 + (size_t)bh * SLEN * HDIM;
  const u16* vR = Vr + ((size_t)bh * RLEN + bar * 32) * HDIM;

  {
    int keyo = tid >> 3, dg = (tid & 7) * 8;
#pragma unroll
    for (int it = 0; it < 3; ++it) {
      int key = it * 32 + keyo;
      const u16* src = (key < 64) ? (vS + key * 64 + dg) : (vR + (key - 64) * 64 + dg);
      uint4 v = *(const uint4*)src;
#pragma unroll
      for (int wi = 0; wi < 4; ++wi) {
        u32 wv = (wi == 0) ? v.x : (wi == 1) ? v.y : (wi == 2) ? v.z : v.w;
        Vt[dg + 2 * wi][key]     = (u16)(wv & 0xffffu);
        Vt[dg + 2 * wi + 1][key] = (u16)(wv >> 16);
      }
    }
  }

#pragma unroll
  for (int i = 0; i < 3; ++i) {
    int t = w * 3 + i, r = t / 6, c = t % 6;
    const u16* arow = qB + (r * 16 + l15) * 64 + lg * 8;
    const u16* brow = (c < 4) ? (kS + (c * 16 + l15) * 64 + lg * 8)
                              : (kR + ((c - 4) * 16 + l15) * 64 + lg * 8);
    f32x4 acc = {};
    acc = __builtin_amdgcn_mfma_f32_16x16x32_bf16(*(const short8*)arow,
                                                  *(const short8*)brow, acc, 0, 0, 0);
    acc = __builtin_amdgcn_mfma_f32_16x16x32_bf16(*(const short8*)(arow + 32),
                                                  *(const short8*)(brow + 32), acc, 0, 0, 0);
#pragma unroll
    for (int j = 0; j < 4; ++j)
      Sf[r * 16 + lg * 4 + j][c * 16 + l15] = acc[j] * 0.125f;
  }
  __syncthreads();

  {
    int r = w * 8 + (lane >> 3), sub = lane & 7;
    float vals[12];
    float mx = -1e30f;
#pragma unroll
    for (int j = 0; j < 12; ++j) {
      int c = sub + 8 * j;
      bool valid = (c < nS) || (c >= 64 && c < 96 && (c - 64) <= r);
      float v = valid ? Sf[r][c] : -1e30f;
      vals[j] = v;
      mx = fmaxf(mx, v);
    }
#pragma unroll
    for (int off = 1; off < 8; off <<= 1) mx = fmaxf(mx, __shfl_xor(mx, off));
    float sm = 0.f;
#pragma unroll
    for (int j = 0; j < 12; ++j) {
      vals[j] = __expf(vals[j] - mx);
      sm += vals[j];
    }
#pragma unroll
    for (int off = 1; off < 8; off <<= 1) sm += __shfl_xor(sm, off);
    float inv = 1.f / sm;
#pragma unroll
    for (int j = 0; j < 12; ++j) {
      int c = sub + 8 * j;
      Pb[r][c] = f2bf(vals[j] * inv);
    }
  }
  __syncthreads();

#pragma unroll
  for (int i = 0; i < 2; ++i) {
    int t = w * 2 + i, r = t >> 2, dc = t & 3;
    f32x4 acc = {};
#pragma unroll
    for (int ks = 0; ks < 3; ++ks) {
      short8 a = *(const short8*)&Pb[r * 16 + l15][ks * 32 + lg * 8];
      short8 bb = *(const short8*)&Vt[dc * 16 + l15][ks * 32 + lg * 8];
      acc = __builtin_amdgcn_mfma_f32_16x16x32_bf16(a, bb, acc, 0, 0, 0);
    }
    int d = dc * 16 + l15;
#pragma unroll
    for (int j = 0; j < 4; ++j) {
      int qq = r * 16 + lg * 4 + j;
      int tt = bar * 32 + qq;
      outA[((size_t)(b * RLEN + tt)) * EMBED + h * 64 + d] = f2bf(acc[j]);
    }
  }
}

// ---------- host ----------
extern "C" void kernel_launch(void* const* d_in, const int* in_sizes, int n_in,
                              void* d_out, int out_size, void* d_ws, size_t ws_size,
                              hipStream_t stream) {
  const float* sum_x = (const float*)d_in[0];
  const float* reg_x = (const float*)d_in[1];
  const float* W[10]; const float* Bv[10];
  for (int i = 0; i < 10; ++i) {
    W[i] = (const float*)d_in[4 + 2 * i];
    Bv[i] = (const float*)d_in[5 + 2 * i];
  }

  char* ws = (char*)d_ws;
  size_t off = 0;
  auto alloc = [&](size_t bytes) -> void* {
    void* p = ws + off;
    off += (bytes + 255) & ~(size_t)255;
    return p;
  };

  const size_t SX = (size_t)NBATCH * SLEN * EMBED;
  const size_t RX = (size_t)NBATCH * RLEN * EMBED;

  float* cosT = (float*)alloc((size_t)TOTKV * 32 * 4);
  float* sinT = (float*)alloc((size_t)TOTKV * 32 * 4);
  u16* sxb = (u16*)alloc(SX * 2);
  u16* rxb = (u16*)alloc(RX * 2);
  u16* Wt  = (u16*)alloc((size_t)10 * EMBED * EMBED * 2);
  u16* Qs = (u16*)alloc(SX * 2);
  u16* Ks = (u16*)alloc(SX * 2);
  u16* Vs = (u16*)alloc(SX * 2);
  u16* Qr = (u16*)alloc(RX * 2);
  u16* Kr = (u16*)alloc(RX * 2);
  u16* Vr = (u16*)alloc(RX * 2);
  u16* sattn = (u16*)alloc(SX * 2);
  u16* Ks2 = (u16*)alloc(SX * 2);
  u16* Vs2 = (u16*)alloc(SX * 2);
  u16* rattn = (u16*)alloc(RX * 2);
  float* part = (float*)alloc((size_t)12 * 128 * EMBED * 4);   // 3 z x 4 ks x 128 x 1024 f32
  (void)ws_size; (void)in_sizes; (void)n_in; (void)out_size;

  WSrc wsrc;
  for (int i = 0; i < 10; ++i) wsrc.p[i] = W[i];

  // fused pre-pass: weight transpose + f2bf (reg, sum) + rope table
  prepass_k<<<7048, 256, 0, stream>>>(wsrc, Wt, sum_x, sxb, reg_x, rxb, cosT, sinT);

  // fused QKV: light sum split-K partials (by<4, dispatched first) + reg QKV tiles
  qkvf_k<<<dim3(8, 36, 3), 256, 0, stream>>>(rxb, sxb, Wt,
      Bv[4], Bv[5], Bv[6], Qr, Kr, Vr, part, cosT, sinT);
  // sum QKV reduce (rope + headsplit)
  sumqkv_reduce_k<<<dim3(256, 3), 256, 0, stream>>>(part, Bv[0], Bv[1], Bv[2],
      Qs, Ks, Vs, cosT, sinT);
  // stage-1 attention -> sattn
  attn1_k<<<512, 256, 0, stream>>>(Qs, Ks, Vs, Kr, Vr, sattn);
  // k2/v2 + summary out-projection via split-K + reduce
  float* outS = (float*)d_out;
  float* outR = outS + SX;
  splitk_k<<<dim3(8, 4, 3), 256, 0, stream>>>(sattn, Wt, 8, 9, 3, part);
  sat_reduce_k<<<dim3(256, 3), 256, 0, stream>>>(part, Bv[8], Bv[9], Bv[3],
      Ks2, Vs2, outS);
  // stage-2 attention -> rattn
  attn2_k<<<dim3(64, 32), 256, 0, stream>>>(Qr, Kr, Vr, Ks2, Vs2, rattn);
  // regular out-projection -> d_out (128x64 tiles, 512 blocks, BK=64)
  gemm64_k<<<dim3(16, 32), 256, 0, stream>>>(rattn, Wt + (size_t)7 * EMBED * EMBED, Bv[7], outR);
}

// Round 20
// 120.073 us; speedup vs baseline: 1.0968x; 1.0968x over previous
//
#include <hip/hip_runtime.h>
#include <stdint.h>

typedef unsigned short u16;
typedef unsigned int u32;
typedef __attribute__((ext_vector_type(8))) short short8;
typedef __attribute__((ext_vector_type(4))) float f32x4;

#define EMBED 1024
#define HEADS 16
#define HDIM 64
#define NBATCH 2
#define SLEN 64
#define RLEN 2048
#define TOTKV (SLEN + RLEN)   // 2112

struct WSrc { const float* p[10]; };

// ---------- small helpers ----------
__device__ __forceinline__ float bf2f(u16 u) {
  union { u32 i; float f; } v; v.i = ((u32)u) << 16; return v.f;
}
__device__ __forceinline__ u16 f2bf(float f) {
  union { float f; u32 i; } v; v.f = f;
  return (u16)((v.i + 0x7fffu + ((v.i >> 16) & 1u)) >> 16);  // RNE
}
__device__ __forceinline__ void up2(u32 u, float& a, float& b) {
  union { u32 i; float f; } x, y;
  x.i = u << 16; y.i = u & 0xffff0000u;
  a = x.f; b = y.f;
}
__device__ __forceinline__ void gload16(const void* g, void* l) {
  __builtin_amdgcn_global_load_lds((const __attribute__((address_space(1))) u32*)g,
                                   (__attribute__((address_space(3))) u32*)l, 16, 0, 0);
}

// ---------- fused pre-pass (r11/r14/r17/r18 proven) ----------
__global__ __launch_bounds__(256)
void prepass_k(WSrc wsrc, u16* __restrict__ Wt,
               const float* __restrict__ sum_x, u16* __restrict__ sxb,
               const float* __restrict__ reg_x, u16* __restrict__ rxb,
               float* __restrict__ cosT, float* __restrict__ sinT)
{
  __shared__ float tile[64][65];
  int b = blockIdx.x, t = threadIdx.x;
  if (b < 2560) {
    int z = b >> 8, rem = b & 255;
    int n0 = (rem & 15) * 64, k0 = (rem >> 4) * 64;
    const float* src = wsrc.p[z];
    u16* out = Wt + (size_t)z * (EMBED * (size_t)EMBED);
    int r0 = t >> 4, c0 = (t & 15) * 4;
#pragma unroll
    for (int i = 0; i < 4; ++i) {
      int r = i * 16 + r0;
      float4 v = *(const float4*)(src + (size_t)(k0 + r) * EMBED + n0 + c0);
      tile[r][c0] = v.x; tile[r][c0 + 1] = v.y; tile[r][c0 + 2] = v.z; tile[r][c0 + 3] = v.w;
    }
    __syncthreads();
#pragma unroll
    for (int i = 0; i < 4; ++i) {
      int n = i * 16 + r0;
      uint2 o;
      o.x = (u32)f2bf(tile[c0][n]) | ((u32)f2bf(tile[c0 + 1][n]) << 16);
      o.y = (u32)f2bf(tile[c0 + 2][n]) | ((u32)f2bf(tile[c0 + 3][n]) << 16);
      *(uint2*)(out + (size_t)(n0 + n) * EMBED + k0 + c0) = o;
    }
  } else if (b < 6656) {
    int i = ((b - 2560) * 256 + t) * 4;
    if (i < (int)((size_t)NBATCH * RLEN * EMBED)) {
      float4 v = *(const float4*)(reg_x + i);
      uint2 o;
      o.x = (u32)f2bf(v.x) | ((u32)f2bf(v.y) << 16);
      o.y = (u32)f2bf(v.z) | ((u32)f2bf(v.w) << 16);
      *(uint2*)(rxb + i) = o;
    }
  } else if (b < 6784) {
    int i = ((b - 6656) * 256 + t) * 4;
    if (i < (int)((size_t)NBATCH * SLEN * EMBED)) {
      float4 v = *(const float4*)(sum_x + i);
      uint2 o;
      o.x = (u32)f2bf(v.x) | ((u32)f2bf(v.y) << 16);
      o.y = (u32)f2bf(v.z) | ((u32)f2bf(v.w) << 16);
      *(uint2*)(sxb + i) = o;
    }
  } else {
    int idx = (b - 6784) * 256 + t;
    if (idx < TOTKV * 32) {
      int pos = idx >> 5, i = idx & 31;
      float inv = powf(10000.0f, -(float)i / 32.0f);
      float a = (float)pos * inv;
      float s, c;
      sincosf(a, &s, &c);
      cosT[idx] = c; sinT[idx] = s;
    }
  }
}

// ---------- BK=32 core with K range (r17/r18 proven) ----------
__device__ __forceinline__ void gemm_core32r(const u16* __restrict__ A, const u16* __restrict__ Wt,
                                             int rowBase, int colBase, int lane, int w,
                                             u16* As, u16* Bs, f32x4 (&acc)[4][4],
                                             int kBeg, int kEnd) {
  int wr = w >> 1, wc = w & 1;
  int lr = lane >> 2, l4 = lane & 3;
  const u16* srcA0 = A + (size_t)(rowBase + w * 16 + lr) * EMBED + l4 * 8;
  const u16* srcA1 = srcA0 + 64 * EMBED;
  const u16* srcB0 = Wt + (size_t)(colBase + w * 16 + lr) * EMBED + l4 * 8;
  const u16* srcB1 = srcB0 + 64 * EMBED;
  u16* dstA = As + w * 512;
  u16* dstB = Bs + w * 512;
  int aoff = (lane & 15) * 32 + (lane >> 4) * 8;
  const u16* fA = As + wr * 2048 + aoff;
  const u16* fB = Bs + wc * 2048 + aoff;

  for (int k0 = kBeg; k0 < kEnd; k0 += 32) {
    gload16(srcA0 + k0, dstA);
    gload16(srcA1 + k0, dstA + 2048);
    gload16(srcB0 + k0, dstB);
    gload16(srcB1 + k0, dstB + 2048);
    __syncthreads();
    short8 af[4], bfv[4];
#pragma unroll
    for (int mi = 0; mi < 4; ++mi) af[mi] = *(const short8*)(fA + mi * 512);
#pragma unroll
    for (int ni = 0; ni < 4; ++ni) bfv[ni] = *(const short8*)(fB + ni * 512);
#pragma unroll
    for (int mi = 0; mi < 4; ++mi)
#pragma unroll
      for (int ni = 0; ni < 4; ++ni)
        acc[mi][ni] = __builtin_amdgcn_mfma_f32_16x16x32_bf16(af[mi], bfv[ni], acc[mi][ni], 0, 0, 0);
    __syncthreads();
  }
}

// mode 0: bf16 headsplit + rope; mode 1: bf16 headsplit; mode 2: f32 row-major
__device__ __forceinline__ void gemm_epilogue(f32x4 (&acc)[4][4], int mode, void* outp,
                                              const float* bias, int rowBase, int colBase,
                                              int L, int posoff, int lane, int w,
                                              const float* cosT, const float* sinT) {
  int wr = w >> 1, wc = w & 1;
  int c15 = lane & 15, rgrp = (lane >> 4) * 4;
  if (mode == 2) {
    float* out = (float*)outp;
#pragma unroll
    for (int mi = 0; mi < 4; ++mi)
#pragma unroll
      for (int r = 0; r < 4; ++r) {
        int m = rowBase + wr * 64 + mi * 16 + rgrp + r;
#pragma unroll
        for (int ni = 0; ni < 4; ++ni) {
          int n = colBase + wc * 64 + ni * 16 + c15;
          out[(size_t)m * EMBED + n] = acc[mi][ni][r] + bias[n];
        }
      }
  } else {
    u16* out = (u16*)outp;
    int h = (colBase >> 6) + wc;
    bool dorope = (mode == 0);
#pragma unroll
    for (int mi = 0; mi < 4; ++mi)
#pragma unroll
      for (int r = 0; r < 4; ++r) {
        int m = rowBase + wr * 64 + mi * 16 + rgrp + r;
        int bidx = (m >= L) ? 1 : 0;
        int l = m - bidx * L;
        size_t obase = ((size_t)(bidx * HEADS + h) * L + l) * HDIM;
        if (dorope) {
          int pos = posoff + l;
#pragma unroll
          for (int ni = 0; ni < 2; ++ni) {
            int d = ni * 16 + c15;
            float c = cosT[pos * 32 + d], s = sinT[pos * 32 + d];
            float x0 = acc[mi][ni][r] + bias[h * 64 + d];
            float x2 = acc[mi][ni + 2][r] + bias[h * 64 + d + 32];
            out[obase + d]      = f2bf(x0 * c - x2 * s);
            out[obase + d + 32] = f2bf(x2 * c + x0 * s);
          }
        } else {
#pragma unroll
          for (int ni = 0; ni < 4; ++ni) {
            int d = ni * 16 + c15;
            out[obase + d] = f2bf(acc[mi][ni][r] + bias[h * 64 + d]);
          }
        }
      }
  }
}

// ---------- reg QKV: grid (8, 32, 3) = 768 blocks, BK=32 core (r17/r18-measured 41 us) ----------
__global__ __launch_bounds__(256)
void regqkv_k(const u16* __restrict__ rxb, const u16* __restrict__ Wt_all,
              const float* b0, const float* b1, const float* b2,
              u16* Qr, u16* Kr, u16* Vr,
              const float* __restrict__ cosT, const float* __restrict__ sinT)
{
  __shared__ __align__(16) u16 As[4096];
  __shared__ __align__(16) u16 Bs[4096];
  int bx = blockIdx.x, by = blockIdx.y, bz = blockIdx.z;
  int lane = threadIdx.x & 63, w = threadIdx.x >> 6;
  const u16* Wt = Wt_all + (size_t)(4 + bz) * EMBED * EMBED;
  const float* bias = (bz == 0) ? b0 : ((bz == 1) ? b1 : b2);
  u16* out = (bz == 0) ? Qr : (bz == 1 ? Kr : Vr);
  int mode = (bz < 2) ? 0 : 1;

  f32x4 acc[4][4] = {};
  gemm_core32r(rxb, Wt, by * 128, bx * 128, lane, w, As, Bs, acc, 0, EMBED);
  gemm_epilogue(acc, mode, out, bias, by * 128, bx * 128, RLEN, SLEN, lane, w, cosT, sinT);
}

// ---------- generic split-K partial: grid (8, 4, 3); A[128 x 1024] @ W(z) over K quarter ----------
__global__ __launch_bounds__(256)
void splitk_k(const u16* __restrict__ A, const u16* __restrict__ Wt_all,
              int wi0, int wi1, int wi2, float* __restrict__ part)
{
  __shared__ __align__(16) u16 As[4096];
  __shared__ __align__(16) u16 Bs[4096];
  int bx = blockIdx.x, ks = blockIdx.y, bz = blockIdx.z;
  int lane = threadIdx.x & 63, w = threadIdx.x >> 6;
  int widx = (bz == 0) ? wi0 : ((bz == 1) ? wi1 : wi2);
  const u16* Wt = Wt_all + (size_t)widx * EMBED * EMBED;
  int colBase = bx * 128;

  f32x4 acc[4][4] = {};
  gemm_core32r(A, Wt, 0, colBase, lane, w, As, Bs, acc, ks * 256, ks * 256 + 256);

  float* outp = part + ((size_t)(bz * 4 + ks)) * (128 * EMBED);
  int wr = w >> 1, wc = w & 1, c15 = lane & 15, rgrp = (lane >> 4) * 4;
#pragma unroll
  for (int mi = 0; mi < 4; ++mi)
#pragma unroll
    for (int r = 0; r < 4; ++r) {
      int m = wr * 64 + mi * 16 + rgrp + r;
#pragma unroll
      for (int ni = 0; ni < 4; ++ni) {
        int n = colBase + wc * 64 + ni * 16 + c15;
        outp[(size_t)m * EMBED + n] = acc[mi][ni][r];
      }
    }
}

// ---------- sum QKV reduce: grid (256, 3); rope on z<2 (r17/r18 proven) ----------
__global__ __launch_bounds__(256)
void sumqkv_reduce_k(const float* __restrict__ part,
                     const float* b0, const float* b1, const float* b2,
                     u16* Qs, u16* Ks, u16* Vs,
                     const float* __restrict__ cosT, const float* __restrict__ sinT)
{
  int z = blockIdx.y;
  int idx = blockIdx.x * 256 + threadIdx.x;
  int m = idx >> 9, rest = idx & 511;
  int h = rest >> 5, d = rest & 31;
  const float* p = part + (size_t)z * 4 * (128 * EMBED);
  const float* bias = (z == 0) ? b0 : ((z == 1) ? b1 : b2);
  u16* out = (z == 0) ? Qs : ((z == 1) ? Ks : Vs);
  int n0 = h * 64 + d, n1 = n0 + 32;
  float a0 = 0.f, a1 = 0.f;
#pragma unroll
  for (int ks = 0; ks < 4; ++ks) {
    a0 += p[(size_t)ks * (128 * EMBED) + (size_t)m * EMBED + n0];
    a1 += p[(size_t)ks * (128 * EMBED) + (size_t)m * EMBED + n1];
  }
  a0 += bias[n0];
  a1 += bias[n1];
  int b = m >> 6, l = m & 63;
  size_t obase = ((size_t)(b * HEADS + h) * SLEN + l) * HDIM;
  if (z < 2) {
    float c = cosT[l * 32 + d], s = sinT[l * 32 + d];
    out[obase + d]      = f2bf(a0 * c - a1 * s);
    out[obase + d + 32] = f2bf(a1 * c + a0 * s);
  } else {
    out[obase + d]      = f2bf(a0);
    out[obase + d + 32] = f2bf(a1);
  }
}

// ---------- sattn reduce: grid (256, 3); z 0/1 -> K2/V2 headsplit (no rope), z 2 -> outS f32 ----------
__global__ __launch_bounds__(256)
void sat_reduce_k(const float* __restrict__ part,
                  const float* b0, const float* b1, const float* b2,
                  u16* Ks2, u16* Vs2, float* __restrict__ outS)
{
  int z = blockIdx.y;
  int idx = blockIdx.x * 256 + threadIdx.x;
  int m = idx >> 9, rest = idx & 511;
  int h = rest >> 5, d = rest & 31;
  const float* p = part + (size_t)z * 4 * (128 * EMBED);
  const float* bias = (z == 0) ? b0 : ((z == 1) ? b1 : b2);
  int n0 = h * 64 + d, n1 = n0 + 32;
  float a0 = 0.f, a1 = 0.f;
#pragma unroll
  for (int ks = 0; ks < 4; ++ks) {
    a0 += p[(size_t)ks * (128 * EMBED) + (size_t)m * EMBED + n0];
    a1 += p[(size_t)ks * (128 * EMBED) + (size_t)m * EMBED + n1];
  }
  a0 += bias[n0];
  a1 += bias[n1];
  if (z < 2) {
    u16* out = (z == 0) ? Ks2 : Vs2;
    int b = m >> 6, l = m & 63;
    size_t obase = ((size_t)(b * HEADS + h) * SLEN + l) * HDIM;
    out[obase + d]      = f2bf(a0);
    out[obase + d + 32] = f2bf(a1);
  } else {
    outS[(size_t)m * EMBED + n0] = a0;
    outS[(size_t)m * EMBED + n1] = a1;
  }
}

// ---------- 128x64-tile GEMM, BK=64 (r13/r14/r17/r18 green): reg out-projection ----------
__global__ __launch_bounds__(256)
void gemm64_k(const u16* __restrict__ A, const u16* __restrict__ Wt,
              const float* __restrict__ bias, float* __restrict__ out)
{
  __shared__ __align__(128) u16 As[8192];   // 128 x 64
  __shared__ __align__(128) u16 Bs[4096];   // 64 x 64
  int rowBase = blockIdx.y * 128, colBase = blockIdx.x * 64;
  int lane = threadIdx.x & 63, w = threadIdx.x >> 6;
  int lrow = lane >> 3, lcol = ((lane & 7) ^ lrow) * 8;

  const u16* srcA = A + (size_t)(rowBase + w * 16 + lrow) * EMBED + lcol;
  const u16* srcB = Wt + (size_t)(colBase + w * 16 + lrow) * EMBED + lcol;
  u16* dA = As + w * 1024;
  u16* dB = Bs + w * 1024;
  int l15 = lane & 15, lg = lane >> 4;
  int aoff = l15 * 64 + ((lg ^ (l15 & 7)) * 8);
  const u16* fA = As + w * 2048 + aoff;
  const u16* fB = Bs + aoff;

  f32x4 acc[2][4] = {};
  for (int k0 = 0; k0 < EMBED; k0 += 64) {
    gload16(srcA + k0, dA);
    gload16(srcA + 8 * EMBED + k0, dA + 512);
    gload16(srcA + 64 * EMBED + k0, dA + 4096);
    gload16(srcA + 72 * EMBED + k0, dA + 4608);
    gload16(srcB + k0, dB);
    gload16(srcB + 8 * EMBED + k0, dB + 512);
    __syncthreads();
#pragma unroll
    for (int ks = 0; ks < 2; ++ks) {
      const u16* fAk = (const u16*)((uintptr_t)fA ^ (unsigned)(ks << 6));
      const u16* fBk = (const u16*)((uintptr_t)fB ^ (unsigned)(ks << 6));
      short8 af[2], bfv[4];
#pragma unroll
      for (int mi = 0; mi < 2; ++mi) af[mi] = *(const short8*)(fAk + mi * 1024);
#pragma unroll
      for (int ni = 0; ni < 4; ++ni) bfv[ni] = *(const short8*)(fBk + ni * 1024);
#pragma unroll
      for (int mi = 0; mi < 2; ++mi)
#pragma unroll
        for (int ni = 0; ni < 4; ++ni)
          acc[mi][ni] = __builtin_amdgcn_mfma_f32_16x16x32_bf16(af[mi], bfv[ni], acc[mi][ni], 0, 0, 0);
    }
    __syncthreads();
  }

  int c15 = lane & 15, rgrp = (lane >> 4) * 4;
#pragma unroll
  for (int mi = 0; mi < 2; ++mi)
#pragma unroll
    for (int r = 0; r < 4; ++r) {
      int m = rowBase + w * 32 + mi * 16 + rgrp + r;
#pragma unroll
      for (int ni = 0; ni < 4; ++ni) {
        int n = colBase + ni * 16 + c15;
        out[(size_t)m * EMBED + n] = acc[mi][ni][r] + bias[n];
      }
    }
}

// ---------- attention helpers ----------
__device__ __forceinline__ void loadq(const u16* qrow, float* qf) {
  const uint4* qp = (const uint4*)qrow;
#pragma unroll
  for (int c = 0; c < 8; ++c) {
    uint4 u = qp[c];
    up2(u.x, qf[c * 8 + 0], qf[c * 8 + 1]);
    up2(u.y, qf[c * 8 + 2], qf[c * 8 + 3]);
    up2(u.z, qf[c * 8 + 4], qf[c * 8 + 5]);
    up2(u.w, qf[c * 8 + 6], qf[c * 8 + 7]);
  }
}
__device__ __forceinline__ float dot64(const float* qf, const u16* krow) {
  const uint4* kp = (const uint4*)krow;
  float s = 0.f;
#pragma unroll
  for (int c = 0; c < 8; ++c) {
    uint4 u = kp[c];
    float a0, a1, a2, a3, a4, a5, a6, a7;
    up2(u.x, a0, a1); up2(u.y, a2, a3); up2(u.z, a4, a5); up2(u.w, a6, a7);
    s += qf[c * 8 + 0] * a0 + qf[c * 8 + 1] * a1 + qf[c * 8 + 2] * a2 + qf[c * 8 + 3] * a3
       + qf[c * 8 + 4] * a4 + qf[c * 8 + 5] * a5 + qf[c * 8 + 6] * a6 + qf[c * 8 + 7] * a7;
  }
  return s;
}

// ---------- stage-1 attention: one query per wave ----------
__global__ __launch_bounds__(256)
void attn1_k(const u16* __restrict__ Qs, const u16* __restrict__ Ks,
             const u16* __restrict__ Vs, const u16* __restrict__ Kr,
             const u16* __restrict__ Vr, u16* __restrict__ outA)
{
  int gw = blockIdx.x * 4 + (threadIdx.x >> 6);
  int bh = gw >> 6, qi = gw & 63;
  int b = bh >> 4, h = bh & 15;
  int lane = threadIdx.x & 63;
  const u16* qB = Qs + (size_t)bh * SLEN * HDIM;
  const u16* kS = Ks + (size_t)bh * SLEN * HDIM;
  const u16* vS = Vs + (size_t)bh * SLEN * HDIM;
  const u16* kR = Kr + (size_t)bh * RLEN * HDIM;
  const u16* vR = Vr + (size_t)bh * RLEN * HDIM;

  float qf[64];
  loadq(qB + qi * HDIM, qf);
  bool v1 = (lane <= qi);
  bool v2 = (lane < 32);
  float s1 = v1 ? dot64(qf, kS + lane * HDIM) : 0.f;
  float s2 = v2 ? dot64(qf, kR + (qi * 32 + lane) * HDIM) : 0.f;
  float sc1 = v1 ? s1 * 0.125f : -1e30f;
  float sc2 = v2 ? s2 * 0.125f : -1e30f;
  float mx = fmaxf(sc1, sc2);
#pragma unroll
  for (int off = 32; off; off >>= 1) mx = fmaxf(mx, __shfl_xor(mx, off));
  float e1 = v1 ? __expf(sc1 - mx) : 0.f;
  float e2 = v2 ? __expf(sc2 - mx) : 0.f;
  float sm = e1 + e2;
#pragma unroll
  for (int off = 32; off; off >>= 1) sm += __shfl_xor(sm, off);
  float inv = 1.f / sm;

  float a0 = 0.f, a1 = 0.f, a2 = 0.f, a3 = 0.f;
  const u16* vrow = vR + (size_t)qi * 32 * HDIM + lane;
#pragma unroll
  for (int j = 0; j < 64; j += 4) {
    a0 += __shfl(e1, j + 0) * bf2f(vS[(j + 0) * HDIM + lane]);
    a1 += __shfl(e1, j + 1) * bf2f(vS[(j + 1) * HDIM + lane]);
    a2 += __shfl(e1, j + 2) * bf2f(vS[(j + 2) * HDIM + lane]);
    a3 += __shfl(e1, j + 3) * bf2f(vS[(j + 3) * HDIM + lane]);
  }
#pragma unroll
  for (int j = 0; j < 32; j += 4) {
    a0 += __shfl(e2, j + 0) * bf2f(vrow[(j + 0) * HDIM]);
    a1 += __shfl(e2, j + 1) * bf2f(vrow[(j + 1) * HDIM]);
    a2 += __shfl(e2, j + 2) * bf2f(vrow[(j + 2) * HDIM]);
    a3 += __shfl(e2, j + 3) * bf2f(vrow[(j + 3) * HDIM]);
  }
  float accv = (a0 + a1) + (a2 + a3);
  outA[((size_t)(b * SLEN + qi)) * EMBED + h * HDIM + lane] = f2bf(accv * inv);
}

// ---------- stage-2 attention: MFMA per (b,h,bar) block (r14/r17/r18 green) ----------
__global__ __launch_bounds__(256)
void attn2_k(const u16* __restrict__ Qr, const u16* __restrict__ Kr,
             const u16* __restrict__ Vr, const u16* __restrict__ Ks2,
             const u16* __restrict__ Vs2, u16* __restrict__ outA)
{
  __shared__ __align__(16) float Sf[32][104];
  __shared__ __align__(16) u16 Pb[32][104];
  __shared__ __align__(16) u16 Vt[64][104];

  int bar = blockIdx.x, bh = blockIdx.y;
  int b = bh >> 4, h = bh & 15;
  int nS = bar + 1;
  int tid = threadIdx.x, lane = tid & 63, w = tid >> 6;
  int l15 = lane & 15, lg = lane >> 4;

  const u16* qB = Qr + ((size_t)bh * RLEN + bar * 32) * HDIM;
  const u16* kS = Ks2 + (size_t)bh * SLEN * HDIM;
  const u16* kR = Kr + ((size_t)bh * RLEN + bar * 32) * HDIM;
  const u16* vS = Vs2 + (size_t)bh * SLEN * HDIM;
  const u16* vR = Vr + ((size_t)bh * RLEN + bar * 32) * HDIM;

  {
    int keyo = tid >> 3, dg = (tid & 7) * 8;
#pragma unroll
    for (int it = 0; it < 3; ++it) {
      int key = it * 32 + keyo;
      const u16* src = (key < 64) ? (vS + key * 64 + dg) : (vR + (key - 64) * 64 + dg);
      uint4 v = *(const uint4*)src;
#pragma unroll
      for (int wi = 0; wi < 4; ++wi) {
        u32 wv = (wi == 0) ? v.x : (wi == 1) ? v.y : (wi == 2) ? v.z : v.w;
        Vt[dg + 2 * wi][key]     = (u16)(wv & 0xffffu);
        Vt[dg + 2 * wi + 1][key] = (u16)(wv >> 16);
      }
    }
  }

#pragma unroll
  for (int i = 0; i < 3; ++i) {
    int t = w * 3 + i, r = t / 6, c = t % 6;
    const u16* arow = qB + (r * 16 + l15) * 64 + lg * 8;
    const u16* brow = (c < 4) ? (kS + (c * 16 + l15) * 64 + lg * 8)
                              : (kR + ((c - 4) * 16 + l15) * 64 + lg * 8);
    f32x4 acc = {};
    acc = __builtin_amdgcn_mfma_f32_16x16x32_bf16(*(const short8*)arow,
                                                  *(const short8*)brow, acc, 0, 0, 0);
    acc = __builtin_amdgcn_mfma_f32_16x16x32_bf16(*(const short8*)(arow + 32),
                                                  *(const short8*)(brow + 32), acc, 0, 0, 0);
#pragma unroll
    for (int j = 0; j < 4; ++j)
      Sf[r * 16 + lg * 4 + j][c * 16 + l15] = acc[j] * 0.125f;
  }
  __syncthreads();

  {
    int r = w * 8 + (lane >> 3), sub = lane & 7;
    float vals[12];
    float mx = -1e30f;
#pragma unroll
    for (int j = 0; j < 12; ++j) {
      int c = sub + 8 * j;
      bool valid = (c < nS) || (c >= 64 && c < 96 && (c - 64) <= r);
      float v = valid ? Sf[r][c] : -1e30f;
      vals[j] = v;
      mx = fmaxf(mx, v);
    }
#pragma unroll
    for (int off = 1; off < 8; off <<= 1) mx = fmaxf(mx, __shfl_xor(mx, off));
    float sm = 0.f;
#pragma unroll
    for (int j = 0; j < 12; ++j) {
      vals[j] = __expf(vals[j] - mx);
      sm += vals[j];
    }
#pragma unroll
    for (int off = 1; off < 8; off <<= 1) sm += __shfl_xor(sm, off);
    float inv = 1.f / sm;
#pragma unroll
    for (int j = 0; j < 12; ++j) {
      int c = sub + 8 * j;
      Pb[r][c] = f2bf(vals[j] * inv);
    }
  }
  __syncthreads();

#pragma unroll
  for (int i = 0; i < 2; ++i) {
    int t = w * 2 + i, r = t >> 2, dc = t & 3;
    f32x4 acc = {};
#pragma unroll
    for (int ks = 0; ks < 3; ++ks) {
      short8 a = *(const short8*)&Pb[r * 16 + l15][ks * 32 + lg * 8];
      short8 bb = *(const short8*)&Vt[dc * 16 + l15][ks * 32 + lg * 8];
      acc = __builtin_amdgcn_mfma_f32_16x16x32_bf16(a, bb, acc, 0, 0, 0);
    }
    int d = dc * 16 + l15;
#pragma unroll
    for (int j = 0; j < 4; ++j) {
      int qq = r * 16 + lg * 4 + j;
      int tt = bar * 32 + qq;
      outA[((size_t)(b * RLEN + tt)) * EMBED + h * 64 + d] = f2bf(acc[j]);
    }
  }
}

// ---------- host ----------
extern "C" void kernel_launch(void* const* d_in, const int* in_sizes, int n_in,
                              void* d_out, int out_size, void* d_ws, size_t ws_size,
                              hipStream_t stream) {
  const float* sum_x = (const float*)d_in[0];
  const float* reg_x = (const float*)d_in[1];
  const float* W[10]; const float* Bv[10];
  for (int i = 0; i < 10; ++i) {
    W[i] = (const float*)d_in[4 + 2 * i];
    Bv[i] = (const float*)d_in[5 + 2 * i];
  }

  char* ws = (char*)d_ws;
  size_t off = 0;
  auto alloc = [&](size_t bytes) -> void* {
    void* p = ws + off;
    off += (bytes + 255) & ~(size_t)255;
    return p;
  };

  const size_t SX = (size_t)NBATCH * SLEN * EMBED;
  const size_t RX = (size_t)NBATCH * RLEN * EMBED;

  float* cosT = (float*)alloc((size_t)TOTKV * 32 * 4);
  float* sinT = (float*)alloc((size_t)TOTKV * 32 * 4);
  u16* sxb = (u16*)alloc(SX * 2);
  u16* rxb = (u16*)alloc(RX * 2);
  u16* Wt  = (u16*)alloc((size_t)10 * EMBED * EMBED * 2);
  u16* Qs = (u16*)alloc(SX * 2);
  u16* Ks = (u16*)alloc(SX * 2);
  u16* Vs = (u16*)alloc(SX * 2);
  u16* Qr = (u16*)alloc(RX * 2);
  u16* Kr = (u16*)alloc(RX * 2);
  u16* Vr = (u16*)alloc(RX * 2);
  u16* sattn = (u16*)alloc(SX * 2);
  u16* Ks2 = (u16*)alloc(SX * 2);
  u16* Vs2 = (u16*)alloc(SX * 2);
  u16* rattn = (u16*)alloc(RX * 2);
  float* part = (float*)alloc((size_t)12 * 128 * EMBED * 4);   // 3 z x 4 ks x 128 x 1024 f32
  (void)ws_size; (void)in_sizes; (void)n_in; (void)out_size;

  WSrc wsrc;
  for (int i = 0; i < 10; ++i) wsrc.p[i] = W[i];

  // fused pre-pass: weight transpose + f2bf (reg, sum) + rope table
  prepass_k<<<7048, 256, 0, stream>>>(wsrc, Wt, sum_x, sxb, reg_x, rxb, cosT, sinT);

  // sum QKV via split-K (96 blocks, 8 K-steps each) + reduce
  splitk_k<<<dim3(8, 4, 3), 256, 0, stream>>>(sxb, Wt, 0, 1, 2, part);
  sumqkv_reduce_k<<<dim3(256, 3), 256, 0, stream>>>(part, Bv[0], Bv[1], Bv[2],
      Qs, Ks, Vs, cosT, sinT);
  // reg QKV (+RoPE on q,k) — 768 blocks = exactly 3.0 blocks/CU, BK=32 core
  regqkv_k<<<dim3(8, 32, 3), 256, 0, stream>>>(rxb, Wt, Bv[4], Bv[5], Bv[6],
      Qr, Kr, Vr, cosT, sinT);
  // stage-1 attention -> sattn
  attn1_k<<<512, 256, 0, stream>>>(Qs, Ks, Vs, Kr, Vr, sattn);
  // k2/v2 + summary out-projection via split-K + reduce
  float* outS = (float*)d_out;
  float* outR = outS + SX;
  splitk_k<<<dim3(8, 4, 3), 256, 0, stream>>>(sattn, Wt, 8, 9, 3, part);
  sat_reduce_k<<<dim3(256, 3), 256, 0, stream>>>(part, Bv[8], Bv[9], Bv[3],
      Ks2, Vs2, outS);
  // stage-2 attention -> rattn
  attn2_k<<<dim3(64, 32), 256, 0, stream>>>(Qr, Kr, Vr, Ks2, Vs2, rattn);
  // regular out-projection -> d_out (128x64 tiles, 512 blocks, BK=64)
  gemm64_k<<<dim3(16, 32), 256, 0, stream>>>(rattn, Wt + (size_t)7 * EMBED * EMBED, Bv[7], outR);
}